// Round 12
// baseline (578.739 us; speedup 1.0000x reference)
//
#include <hip/hip_runtime.h>

// MultilayeredNetwork v10 = v8(R10, 400us) build + wave-per-row k_layer.
// R11 lesson: VMEM insts are per-wave; float4 shape cut threads 4x and LOST
// (latency/MLP-bound). v10 goes the other way: one WAVE per row, 64 lanes =
// 4 edge-slots x 16 batches, 16-edge unrolled body -> 8 independent VMEM per
// iter per lane, NO LDS staging at all. Cross-slot reduce = 2 int shfl_xor
// adds (exact, order-independent) -> numerics bitwise-identical to R10.
//   build: bcount (196-bin hist) -> bscan -> passA (two-level cursor scatter,
//          PRESCALED vals) -> passB (per-bucket LDS hist+scan -> row_ptr + CSR)
//   per t: wave per row; int32 rn fixed-point accumulate (scale 2^27).
//   final: planes[t][n][b] -> out[b][n][t]

#define N_NEURONS 100000
#define NNZ_CNT   3200000
#define N_SENSORY 5000
#define BATCH     16
#define T_LAYERS  8
#define THRESH    0.01f
#define STEEP     5.0f

#define NB (N_NEURONS * BATCH)
#define NT (N_NEURONS * T_LAYERS)
#define ST (N_SENSORY * T_LAYERS)

#define FXS32     134217728.0f             /* 2^27: exact fp32 prescale */
#define FXI32     7.450580596923828e-9f    /* 2^-27 exact */

#define LBITS   9
#define BROWS   (1 << LBITS)                           /* 512 rows per bucket */
#define NBUCKET ((N_NEURONS + BROWS - 1) / BROWS)      /* 196 */
#define EPB     4096                                   /* edges per build block */
#define NBLK_A  ((NNZ_CNT + EPB - 1) / EPB)            /* 782 */

#define FXSCALE   17592186044416.0f        /* fallback path only (2^44) */
#define FXINV     (1.0 / 17592186044416.0)

__device__ __forceinline__ float thresh_clamp_inp(float u) {
    u = (u >= THRESH) ? u : 0.0f;
    return fminf(u, 1.0f);
}
__device__ __forceinline__ float activate(float y) {
    y = (y >= THRESH) ? y : 0.0f;
    return tanhf(STEEP * y);
}

// ---------------- build (byte-identical to R10) ----------------

__global__ void k_init(const float* __restrict__ inp, float* __restrict__ state0,
                       int* __restrict__ btotal) {
    int i = blockIdx.x * blockDim.x + threadIdx.x;
    if (i >= NB) return;
    int n = i >> 4, b = i & 15;
    float v = 0.0f;
    if (n < N_SENSORY) v = thresh_clamp_inp(inp[b * ST + n * T_LAYERS + 0]);
    state0[i] = v;
    if (i < NBUCKET) btotal[i] = 0;
}

__global__ void __launch_bounds__(1024) k_bcount(const int* __restrict__ rows,
                                                 int* __restrict__ btotal) {
    __shared__ int cnt[NBUCKET];
    const int e0 = blockIdx.x * EPB;
    for (int i = threadIdx.x; i < NBUCKET; i += 1024) cnt[i] = 0;
    __syncthreads();
    #pragma unroll
    for (int i = 0; i < EPB / 1024; ++i) {
        int e = e0 + i * 1024 + threadIdx.x;
        if (e < NNZ_CNT) atomicAdd(&cnt[rows[e] >> LBITS], 1);
    }
    __syncthreads();
    for (int i = threadIdx.x; i < NBUCKET; i += 1024)
        if (cnt[i]) atomicAdd(&btotal[i], cnt[i]);
}

__global__ void k_bscan(const int* __restrict__ btotal, int* __restrict__ bbase,
                        int* __restrict__ bcur, int* __restrict__ row_ptr) {
    __shared__ int lds[256];
    int tid = threadIdx.x;
    int v = (tid < NBUCKET) ? btotal[tid] : 0;
    lds[tid] = v;
    __syncthreads();
    for (int off = 1; off < 256; off <<= 1) {
        int add = (tid >= off) ? lds[tid - off] : 0;
        __syncthreads();
        lds[tid] += add;
        __syncthreads();
    }
    if (tid < NBUCKET) {
        bbase[tid] = lds[tid] - v;
        bcur[tid]  = lds[tid] - v;
    }
    if (tid == 0) { bbase[NBUCKET] = NNZ_CNT; row_ptr[N_NEURONS] = NNZ_CNT; }
}

__global__ void __launch_bounds__(1024) k_passA(const float* __restrict__ vals,
                                                const int* __restrict__ rows,
                                                const int* __restrict__ cols,
                                                int* bcur,
                                                int2* __restrict__ slab) {
    __shared__ int cnt[NBUCKET];
    __shared__ int base[NBUCKET];
    const int e0 = blockIdx.x * EPB;
    for (int i = threadIdx.x; i < NBUCKET; i += 1024) cnt[i] = 0;
    __syncthreads();
    #pragma unroll
    for (int i = 0; i < EPB / 1024; ++i) {
        int e = e0 + i * 1024 + threadIdx.x;
        if (e < NNZ_CNT) atomicAdd(&cnt[rows[e] >> LBITS], 1);
    }
    __syncthreads();
    for (int i = threadIdx.x; i < NBUCKET; i += 1024) {
        int c = cnt[i];
        base[i] = (c > 0) ? atomicAdd(&bcur[i], c) : 0;
        cnt[i] = 0;
    }
    __syncthreads();
    #pragma unroll
    for (int i = 0; i < EPB / 1024; ++i) {
        int e = e0 + i * 1024 + threadIdx.x;
        if (e < NNZ_CNT) {
            int r = rows[e];
            int k = r >> LBITS;
            int pos = base[k] + atomicAdd(&cnt[k], 1);
            slab[pos] = make_int2((cols[e] << LBITS) | (r & (BROWS - 1)),
                                  __float_as_int(vals[e] * FXS32));   // exact prescale
        }
    }
}

__global__ void __launch_bounds__(1024) k_passB(const int* __restrict__ bbase,
                                                const int2* __restrict__ slab,
                                                int2* __restrict__ packed,
                                                int* __restrict__ row_ptr) {
    __shared__ int cnt[BROWS];
    __shared__ int scn[BROWS];
    const int tid = threadIdx.x;
    const int k  = blockIdx.x;
    const int r0 = k * BROWS;
    const int nr = min(BROWS, N_NEURONS - r0);
    const int P0 = bbase[k], P1 = bbase[k + 1];
    for (int i = tid; i < BROWS; i += 1024) cnt[i] = 0;
    __syncthreads();
    for (int i = P0 + tid; i < P1; i += 1024)
        atomicAdd(&cnt[slab[i].x & (BROWS - 1)], 1);
    __syncthreads();
    if (tid < BROWS) scn[tid] = cnt[tid];
    __syncthreads();
    for (int off = 1; off < BROWS; off <<= 1) {
        int add = (tid < BROWS && tid >= off) ? scn[tid - off] : 0;
        __syncthreads();
        if (tid < BROWS) scn[tid] += add;
        __syncthreads();
    }
    if (tid < BROWS) {
        int ex = P0 + scn[tid] - cnt[tid];      // exclusive row base
        if (tid < nr) row_ptr[r0 + tid] = ex;
        scn[tid] = ex;                          // cursor
    }
    __syncthreads();
    for (int i = P0 + tid; i < P1; i += 1024) {
        int2 pe = slab[i];
        int d = atomicAdd(&scn[pe.x & (BROWS - 1)], 1);
        packed[d] = make_int2(pe.x >> LBITS, pe.y);   // (col, prescaled val)
    }
}

// ---------------- fused per-layer SpMM + activation ----------------
// ONE WAVE PER ROW: lane = (jj, b), jj = edge slot 0..3, b = batch 0..15.
// 16-edge unrolled main body -> 8 independent VMEM per lane per iteration.
// Packed loads are 16-lane same-address (HW-merged); gathers cover full 64B
// lines. Cross-slot reduce: 2 exact int shfl_xor adds. No LDS.
__global__ void __launch_bounds__(256) k_layer(const int* __restrict__ row_ptr,
                                               const int2* __restrict__ packed,
                                               const float* __restrict__ state_in,
                                               const float* __restrict__ inp,
                                               float* __restrict__ plane_out,
                                               int t) {
    const int tid = threadIdx.x;
    const int ln  = tid & 63;
    const int jj  = ln >> 4;                    // edge slot
    const int b   = ln & 15;                    // batch
    const int r   = blockIdx.x * 4 + (tid >> 6);   // 25000*4 == N_NEURONS
    const int s = row_ptr[r], e = row_ptr[r + 1];
    int acc = 0;
    int base = s;
    for (; base + 16 <= e; base += 16) {        // full 16-edge steps
        #pragma unroll
        for (int k = 0; k < 4; ++k) {
            int2 q = packed[base + k * 4 + jj];
            acc += __float2int_rn(__int_as_float(q.y) * state_in[(q.x << 4) + b]);
        }
    }
    for (; base < e; base += 4) {               // 4-edge tail steps
        int idx = base + jj;
        if (idx < e) {
            int2 q = packed[idx];
            acc += __float2int_rn(__int_as_float(q.y) * state_in[(q.x << 4) + b]);
        }
    }
    acc += __shfl_xor(acc, 16, 64);             // exact int reduction over jj
    acc += __shfl_xor(acc, 32, 64);
    if (jj == 0) {
        float a = activate((float)acc * FXI32);
        if (t < T_LAYERS - 1) {
            if (r < N_SENSORY) a += thresh_clamp_inp(inp[b * ST + r * T_LAYERS + (t + 1)]);
            a = fminf(a, 1.0f);                 // off-sensory no-op (|tanh|<1)
        }
        plane_out[(r << 4) + b] = a;            // 64B contiguous per row
    }
}

// ---------------- planes[t][n][b] -> out[b][n][t] ----------------
__global__ void k_out(const float* __restrict__ planes, float* __restrict__ out) {
    int i = blockIdx.x * blockDim.x + threadIdx.x;
    if (i >= NB) return;
    int n = i >> 4, b = i & 15;
    float4 o0, o1;
    o0.x = planes[0 * NB + i]; o0.y = planes[1 * NB + i];
    o0.z = planes[2 * NB + i]; o0.w = planes[3 * NB + i];
    o1.x = planes[4 * NB + i]; o1.y = planes[5 * NB + i];
    o1.z = planes[6 * NB + i]; o1.w = planes[7 * NB + i];
    float4* dst = (float4*)&out[b * NT + n * T_LAYERS];
    dst[0] = o0; dst[1] = o1;
}

// ---------------- fallback (atomic fixed-point path, 19.2 MB ws) ----------------
__global__ void k2_init(const float* __restrict__ inp, float* __restrict__ state,
                        long long* __restrict__ acc) {
    int stride = gridDim.x * blockDim.x;
    for (int i = blockIdx.x * blockDim.x + threadIdx.x; i < NB; i += stride) {
        int n = i >> 4, b = i & 15;
        float v = 0.0f;
        if (n < N_SENSORY) v = thresh_clamp_inp(inp[b * ST + n * T_LAYERS + 0]);
        state[i] = v;
        acc[i]   = 0LL;
    }
}
__global__ void __launch_bounds__(256) k2_spmm(const float* __restrict__ vals,
                                               const int* __restrict__ rows,
                                               const int* __restrict__ cols,
                                               const float* __restrict__ state,
                                               long long* acc) {
    int tid = blockIdx.x * blockDim.x + threadIdx.x;
    int b = tid & 15;
    int e = tid >> 4;
    int estride = (gridDim.x * blockDim.x) >> 4;
    for (; e < NNZ_CNT; e += estride) {
        float xv = state[cols[e] * BATCH + b];
        long long fx = llrintf(vals[e] * xv * FXSCALE);
        if (fx != 0LL)
            atomicAdd((unsigned long long*)&acc[rows[e] * BATCH + b], (unsigned long long)fx);
    }
}
__global__ void k2_act_inject(long long* acc, const float* __restrict__ inp,
                              float* __restrict__ state, float* __restrict__ out, int t) {
    int stride = gridDim.x * blockDim.x;
    for (int i = blockIdx.x * blockDim.x + threadIdx.x; i < NB; i += stride) {
        int n = i >> 4, b = i & 15;
        float y = (float)((double)acc[i] * FXINV);
        acc[i] = 0LL;
        float v = activate(y);
        if (n < N_SENSORY) v += thresh_clamp_inp(inp[b * ST + n * T_LAYERS + (t + 1)]);
        v = fminf(v, 1.0f);
        state[i] = v;
        out[b * NT + n * T_LAYERS + t] = v;
    }
}
__global__ void k2_act_final(const long long* __restrict__ acc, float* __restrict__ out) {
    int stride = gridDim.x * blockDim.x;
    for (int i = blockIdx.x * blockDim.x + threadIdx.x; i < NB; i += stride) {
        int n = i >> 4, b = i & 15;
        float y = (float)((double)acc[i] * FXINV);
        out[b * NT + n * T_LAYERS + (T_LAYERS - 1)] = activate(y);
    }
}

extern "C" void kernel_launch(void* const* d_in, const int* in_sizes, int n_in,
                              void* d_out, int out_size, void* d_ws, size_t ws_size,
                              hipStream_t stream) {
    const float* inputs = (const float*)d_in[0];
    const float* vals   = (const float*)d_in[1];
    const int*   rows   = (const int*)  d_in[2];
    const int*   cols   = (const int*)  d_in[3];
    float* out = (float*)d_out;

    const size_t sz_planes = (size_t)T_LAYERS * NB * 4;   // 51.2 MB
    const size_t sz_packed = (size_t)NNZ_CNT * 8;         // 25.6 MB
    const size_t sz_rowptr = ((size_t)N_NEURONS + 2) * 4;
    const size_t sz_bt     = (size_t)(NBUCKET + 8) * 4;
    const size_t REQ = sz_planes + sz_packed + sz_rowptr + 3 * sz_bt;

    const int block = 256;

    if (ws_size >= REQ) {
        char* ws = (char*)d_ws;
        float* planes  = (float*)ws;
        int2*  packed  = (int2*)(ws + sz_planes);
        int*   row_ptr = (int*)(ws + sz_planes + sz_packed);
        int*   btotal  = (int*)(ws + sz_planes + sz_packed + sz_rowptr);
        int*   bbase   = (int*)(ws + sz_planes + sz_packed + sz_rowptr + sz_bt);
        int*   bcur    = (int*)(ws + sz_planes + sz_packed + sz_rowptr + 2 * sz_bt);
        float* state0  = planes + (size_t)(T_LAYERS - 1) * NB;  // planes[7], consumed at t=0
        int2*  slab    = (int2*)planes;   // build scratch aliases planes[0..3]; dead before layers

        const int grid_nb = (NB + block - 1) / block;           // 6250
        const int grid_ly = N_NEURONS / 4;                      // 25000 (4 waves/block)

        k_init<<<grid_nb, block, 0, stream>>>(inputs, state0, btotal);
        k_bcount<<<NBLK_A, 1024, 0, stream>>>(rows, btotal);
        k_bscan<<<1, 256, 0, stream>>>(btotal, bbase, bcur, row_ptr);
        k_passA<<<NBLK_A, 1024, 0, stream>>>(vals, rows, cols, bcur, slab);
        k_passB<<<NBUCKET, 1024, 0, stream>>>(bbase, slab, packed, row_ptr);

        for (int t = 0; t < T_LAYERS; ++t) {
            const float* sin_ = (t == 0) ? state0 : planes + (size_t)(t - 1) * NB;
            k_layer<<<grid_ly, block, 0, stream>>>(row_ptr, packed, sin_, inputs,
                                                   planes + (size_t)t * NB, t);
        }
        k_out<<<grid_nb, block, 0, stream>>>(planes, out);
    } else {
        long long* acc   = (long long*)d_ws;
        float*     state = (float*)(acc + NB);
        const int grid_ew = 2048, grid_sp = 2048;
        k2_init<<<grid_ew, block, 0, stream>>>(inputs, state, acc);
        for (int t = 0; t < T_LAYERS; ++t) {
            k2_spmm<<<grid_sp, block, 0, stream>>>(vals, rows, cols, state, acc);
            if (t < T_LAYERS - 1)
                k2_act_inject<<<grid_ew, block, 0, stream>>>(acc, inputs, state, out, t);
            else
                k2_act_final<<<grid_ew, block, 0, stream>>>(acc, out);
        }
    }
}

// Round 13
// 414.346 us; speedup vs baseline: 1.3968x; 1.3968x over previous
//
#include <hip/hip_runtime.h>

// MultilayeredNetwork v11 = R10 (400us, best) + COLUMN-QUADRANT edge ordering.
// R12 counters: k_layer fetches 109 MB/layer beyond L2 (~83 MB = state-gather
// misses; 6.4MB state > 4MB per-XCD L2, random col order -> ~2.5x reuse only).
// Fix: int32 sums are order-independent, so reorder each row's edges by column
// quadrant (col>>15: 4 x 2MB state windows). Concurrent blocks then walk
// quadrant-by-quadrant -> active gather window ~2MB, L2-resident.
// Implemented ONLY in k_passB's final scatter (4 predicated passes over the
// L2-hot slab). k_layer reverted to exact R10 shape (known-good 35us).
// Numerics bitwise-identical to R10: unbiased __float2int_rn at scale 2^27.

#define N_NEURONS 100000
#define NNZ_CNT   3200000
#define N_SENSORY 5000
#define BATCH     16
#define T_LAYERS  8
#define THRESH    0.01f
#define STEEP     5.0f

#define NB (N_NEURONS * BATCH)
#define NT (N_NEURONS * T_LAYERS)
#define ST (N_SENSORY * T_LAYERS)

#define FXS32     134217728.0f             /* 2^27: exact fp32 prescale */
#define FXI32     7.450580596923828e-9f    /* 2^-27 exact */

#define LBITS   9
#define BROWS   (1 << LBITS)                           /* 512 rows per bucket */
#define NBUCKET ((N_NEURONS + BROWS - 1) / BROWS)      /* 196 */
#define EPB     4096                                   /* edges per build block */
#define NBLK_A  ((NNZ_CNT + EPB - 1) / EPB)            /* 782 */

#define FXSCALE   17592186044416.0f        /* fallback path only (2^44) */
#define FXINV     (1.0 / 17592186044416.0)

__device__ __forceinline__ float thresh_clamp_inp(float u) {
    u = (u >= THRESH) ? u : 0.0f;
    return fminf(u, 1.0f);
}
__device__ __forceinline__ float activate(float y) {
    y = (y >= THRESH) ? y : 0.0f;
    return tanhf(STEEP * y);
}

// ---------------- build ----------------

__global__ void k_init(const float* __restrict__ inp, float* __restrict__ state0,
                       int* __restrict__ btotal) {
    int i = blockIdx.x * blockDim.x + threadIdx.x;
    if (i >= NB) return;
    int n = i >> 4, b = i & 15;
    float v = 0.0f;
    if (n < N_SENSORY) v = thresh_clamp_inp(inp[b * ST + n * T_LAYERS + 0]);
    state0[i] = v;
    if (i < NBUCKET) btotal[i] = 0;
}

__global__ void __launch_bounds__(1024) k_bcount(const int* __restrict__ rows,
                                                 int* __restrict__ btotal) {
    __shared__ int cnt[NBUCKET];
    const int e0 = blockIdx.x * EPB;
    for (int i = threadIdx.x; i < NBUCKET; i += 1024) cnt[i] = 0;
    __syncthreads();
    #pragma unroll
    for (int i = 0; i < EPB / 1024; ++i) {
        int e = e0 + i * 1024 + threadIdx.x;
        if (e < NNZ_CNT) atomicAdd(&cnt[rows[e] >> LBITS], 1);
    }
    __syncthreads();
    for (int i = threadIdx.x; i < NBUCKET; i += 1024)
        if (cnt[i]) atomicAdd(&btotal[i], cnt[i]);
}

__global__ void k_bscan(const int* __restrict__ btotal, int* __restrict__ bbase,
                        int* __restrict__ bcur, int* __restrict__ row_ptr) {
    __shared__ int lds[256];
    int tid = threadIdx.x;
    int v = (tid < NBUCKET) ? btotal[tid] : 0;
    lds[tid] = v;
    __syncthreads();
    for (int off = 1; off < 256; off <<= 1) {
        int add = (tid >= off) ? lds[tid - off] : 0;
        __syncthreads();
        lds[tid] += add;
        __syncthreads();
    }
    if (tid < NBUCKET) {
        bbase[tid] = lds[tid] - v;
        bcur[tid]  = lds[tid] - v;
    }
    if (tid == 0) { bbase[NBUCKET] = NNZ_CNT; row_ptr[N_NEURONS] = NNZ_CNT; }
}

__global__ void __launch_bounds__(1024) k_passA(const float* __restrict__ vals,
                                                const int* __restrict__ rows,
                                                const int* __restrict__ cols,
                                                int* bcur,
                                                int2* __restrict__ slab) {
    __shared__ int cnt[NBUCKET];
    __shared__ int base[NBUCKET];
    const int e0 = blockIdx.x * EPB;
    for (int i = threadIdx.x; i < NBUCKET; i += 1024) cnt[i] = 0;
    __syncthreads();
    #pragma unroll
    for (int i = 0; i < EPB / 1024; ++i) {
        int e = e0 + i * 1024 + threadIdx.x;
        if (e < NNZ_CNT) atomicAdd(&cnt[rows[e] >> LBITS], 1);
    }
    __syncthreads();
    for (int i = threadIdx.x; i < NBUCKET; i += 1024) {
        int c = cnt[i];
        base[i] = (c > 0) ? atomicAdd(&bcur[i], c) : 0;
        cnt[i] = 0;
    }
    __syncthreads();
    #pragma unroll
    for (int i = 0; i < EPB / 1024; ++i) {
        int e = e0 + i * 1024 + threadIdx.x;
        if (e < NNZ_CNT) {
            int r = rows[e];
            int k = r >> LBITS;
            int pos = base[k] + atomicAdd(&cnt[k], 1);
            slab[pos] = make_int2((cols[e] << LBITS) | (r & (BROWS - 1)),
                                  __float_as_int(vals[e] * FXS32));   // exact prescale
        }
    }
}

// pass B: per-bucket slab -> LDS row histogram + scan -> row_ptr, then final CSR
// scatter in 4 COLUMN-QUADRANT passes: each row's packed segment = [q0|q1|q2|q3].
// Quadrant = col>>15 = slab.x>>24 (col<<9 layout). Slab is L2-hot: extra scans cheap.
__global__ void __launch_bounds__(1024) k_passB(const int* __restrict__ bbase,
                                                const int2* __restrict__ slab,
                                                int2* __restrict__ packed,
                                                int* __restrict__ row_ptr) {
    __shared__ int cnt[BROWS];
    __shared__ int scn[BROWS];
    const int tid = threadIdx.x;
    const int k  = blockIdx.x;
    const int r0 = k * BROWS;
    const int nr = min(BROWS, N_NEURONS - r0);
    const int P0 = bbase[k], P1 = bbase[k + 1];
    for (int i = tid; i < BROWS; i += 1024) cnt[i] = 0;
    __syncthreads();
    for (int i = P0 + tid; i < P1; i += 1024)
        atomicAdd(&cnt[slab[i].x & (BROWS - 1)], 1);
    __syncthreads();
    if (tid < BROWS) scn[tid] = cnt[tid];
    __syncthreads();
    for (int off = 1; off < BROWS; off <<= 1) {
        int add = (tid < BROWS && tid >= off) ? scn[tid - off] : 0;
        __syncthreads();
        if (tid < BROWS) scn[tid] += add;
        __syncthreads();
    }
    if (tid < BROWS) {
        int ex = P0 + scn[tid] - cnt[tid];      // exclusive row base
        if (tid < nr) row_ptr[r0 + tid] = ex;
        scn[tid] = ex;                          // cursor
    }
    __syncthreads();
    #pragma unroll
    for (int q = 0; q < 4; ++q) {               // column-quadrant ordered placement
        for (int i = P0 + tid; i < P1; i += 1024) {
            int2 pe = slab[i];
            if ((pe.x >> 24) == q) {            // quadrant of col (col<<9 layout)
                int d = atomicAdd(&scn[pe.x & (BROWS - 1)], 1);
                packed[d] = make_int2(pe.x >> LBITS, pe.y);   // (col, prescaled val)
            }
        }
        __syncthreads();                        // quadrant barrier: q-order within rows
    }
}

// ---------------- fused per-layer SpMM + activation (exact R10 shape) ----------------
// 16-lane group per row (lane = batch). Edge broadcast via LDS (1 ds_write_b64 +
// 16 same-address ds_read_b64) — group is within one wave: no barrier.
// int32 round-to-nearest fixed-point register accumulation (vals prescaled 2^27).
__global__ void __launch_bounds__(256) k_layer(const int* __restrict__ row_ptr,
                                               const int2* __restrict__ packed,
                                               const float* __restrict__ state_in,
                                               const float* __restrict__ inp,
                                               float* __restrict__ plane_out,
                                               int t) {
    __shared__ int2 ebuf[16][17];               // [group][slot], +1 pad
    const int tid = threadIdx.x;
    const int g = tid >> 4, b = tid & 15;
    const int r = blockIdx.x * 16 + g;          // 6250*16 == N_NEURONS exactly
    const int s = row_ptr[r], e = row_ptr[r + 1];
    int acc = 0;
    for (int base = s; base < e; base += 16) {
        int idx = base + b;
        int2 pe = (idx < e) ? packed[idx] : make_int2(0, 0);   // val=0 pad: exact no-op
        ebuf[g][b] = pe;                        // wave-lockstep, in-order DS pipe
        #pragma unroll
        for (int j = 0; j < 16; ++j) {
            int2 q = ebuf[g][j];                // 16-lane same-address broadcast read
            float prod = __int_as_float(q.y) * state_in[q.x * BATCH + b];
            acc += __float2int_rn(prod);        // UNBIASED quantization at 2^-28
        }
    }
    float y = (float)acc * FXI32;
    float a = activate(y);
    if (t < T_LAYERS - 1) {
        if (r < N_SENSORY) a += thresh_clamp_inp(inp[b * ST + r * T_LAYERS + (t + 1)]);
        a = fminf(a, 1.0f);                     // off-sensory no-op (|tanh|<1)
    }
    plane_out[r * BATCH + b] = a;
}

// ---------------- planes[t][n][b] -> out[b][n][t] ----------------
__global__ void k_out(const float* __restrict__ planes, float* __restrict__ out) {
    int i = blockIdx.x * blockDim.x + threadIdx.x;
    if (i >= NB) return;
    int n = i >> 4, b = i & 15;
    float4 o0, o1;
    o0.x = planes[0 * NB + i]; o0.y = planes[1 * NB + i];
    o0.z = planes[2 * NB + i]; o0.w = planes[3 * NB + i];
    o1.x = planes[4 * NB + i]; o1.y = planes[5 * NB + i];
    o1.z = planes[6 * NB + i]; o1.w = planes[7 * NB + i];
    float4* dst = (float4*)&out[b * NT + n * T_LAYERS];
    dst[0] = o0; dst[1] = o1;
}

// ---------------- fallback (atomic fixed-point path, 19.2 MB ws) ----------------
__global__ void k2_init(const float* __restrict__ inp, float* __restrict__ state,
                        long long* __restrict__ acc) {
    int stride = gridDim.x * blockDim.x;
    for (int i = blockIdx.x * blockDim.x + threadIdx.x; i < NB; i += stride) {
        int n = i >> 4, b = i & 15;
        float v = 0.0f;
        if (n < N_SENSORY) v = thresh_clamp_inp(inp[b * ST + n * T_LAYERS + 0]);
        state[i] = v;
        acc[i]   = 0LL;
    }
}
__global__ void __launch_bounds__(256) k2_spmm(const float* __restrict__ vals,
                                               const int* __restrict__ rows,
                                               const int* __restrict__ cols,
                                               const float* __restrict__ state,
                                               long long* acc) {
    int tid = blockIdx.x * blockDim.x + threadIdx.x;
    int b = tid & 15;
    int e = tid >> 4;
    int estride = (gridDim.x * blockDim.x) >> 4;
    for (; e < NNZ_CNT; e += estride) {
        float xv = state[cols[e] * BATCH + b];
        long long fx = llrintf(vals[e] * xv * FXSCALE);
        if (fx != 0LL)
            atomicAdd((unsigned long long*)&acc[rows[e] * BATCH + b], (unsigned long long)fx);
    }
}
__global__ void k2_act_inject(long long* acc, const float* __restrict__ inp,
                              float* __restrict__ state, float* __restrict__ out, int t) {
    int stride = gridDim.x * blockDim.x;
    for (int i = blockIdx.x * blockDim.x + threadIdx.x; i < NB; i += stride) {
        int n = i >> 4, b = i & 15;
        float y = (float)((double)acc[i] * FXINV);
        acc[i] = 0LL;
        float v = activate(y);
        if (n < N_SENSORY) v += thresh_clamp_inp(inp[b * ST + n * T_LAYERS + (t + 1)]);
        v = fminf(v, 1.0f);
        state[i] = v;
        out[b * NT + n * T_LAYERS + t] = v;
    }
}
__global__ void k2_act_final(const long long* __restrict__ acc, float* __restrict__ out) {
    int stride = gridDim.x * blockDim.x;
    for (int i = blockIdx.x * blockDim.x + threadIdx.x; i < NB; i += stride) {
        int n = i >> 4, b = i & 15;
        float y = (float)((double)acc[i] * FXINV);
        out[b * NT + n * T_LAYERS + (T_LAYERS - 1)] = activate(y);
    }
}

extern "C" void kernel_launch(void* const* d_in, const int* in_sizes, int n_in,
                              void* d_out, int out_size, void* d_ws, size_t ws_size,
                              hipStream_t stream) {
    const float* inputs = (const float*)d_in[0];
    const float* vals   = (const float*)d_in[1];
    const int*   rows   = (const int*)  d_in[2];
    const int*   cols   = (const int*)  d_in[3];
    float* out = (float*)d_out;

    const size_t sz_planes = (size_t)T_LAYERS * NB * 4;   // 51.2 MB
    const size_t sz_packed = (size_t)NNZ_CNT * 8;         // 25.6 MB
    const size_t sz_rowptr = ((size_t)N_NEURONS + 2) * 4;
    const size_t sz_bt     = (size_t)(NBUCKET + 8) * 4;
    const size_t REQ = sz_planes + sz_packed + sz_rowptr + 3 * sz_bt;

    const int block = 256;

    if (ws_size >= REQ) {
        char* ws = (char*)d_ws;
        float* planes  = (float*)ws;
        int2*  packed  = (int2*)(ws + sz_planes);
        int*   row_ptr = (int*)(ws + sz_planes + sz_packed);
        int*   btotal  = (int*)(ws + sz_planes + sz_packed + sz_rowptr);
        int*   bbase   = (int*)(ws + sz_planes + sz_packed + sz_rowptr + sz_bt);
        int*   bcur    = (int*)(ws + sz_planes + sz_packed + sz_rowptr + 2 * sz_bt);
        float* state0  = planes + (size_t)(T_LAYERS - 1) * NB;  // planes[7], consumed at t=0
        int2*  slab    = (int2*)planes;   // build scratch aliases planes[0..3]; dead before layers

        const int grid_nb = (NB + block - 1) / block;           // 6250

        k_init<<<grid_nb, block, 0, stream>>>(inputs, state0, btotal);
        k_bcount<<<NBLK_A, 1024, 0, stream>>>(rows, btotal);
        k_bscan<<<1, 256, 0, stream>>>(btotal, bbase, bcur, row_ptr);
        k_passA<<<NBLK_A, 1024, 0, stream>>>(vals, rows, cols, bcur, slab);
        k_passB<<<NBUCKET, 1024, 0, stream>>>(bbase, slab, packed, row_ptr);

        for (int t = 0; t < T_LAYERS; ++t) {
            const float* sin_ = (t == 0) ? state0 : planes + (size_t)(t - 1) * NB;
            k_layer<<<grid_nb, block, 0, stream>>>(row_ptr, packed, sin_, inputs,
                                                   planes + (size_t)t * NB, t);
        }
        k_out<<<grid_nb, block, 0, stream>>>(planes, out);
    } else {
        long long* acc   = (long long*)d_ws;
        float*     state = (float*)(acc + NB);
        const int grid_ew = 2048, grid_sp = 2048;
        k2_init<<<grid_ew, block, 0, stream>>>(inputs, state, acc);
        for (int t = 0; t < T_LAYERS; ++t) {
            k2_spmm<<<grid_sp, block, 0, stream>>>(vals, rows, cols, state, acc);
            if (t < T_LAYERS - 1)
                k2_act_inject<<<grid_ew, block, 0, stream>>>(acc, inputs, state, out, t);
            else
                k2_act_final<<<grid_ew, block, 0, stream>>>(acc, out);
        }
    }
}

// Round 14
// 380.908 us; speedup vs baseline: 1.5194x; 1.0878x over previous
//
#include <hip/hip_runtime.h>

// MultilayeredNetwork v12 = R10 (400us, best verified) + packed-stream prefetch
// in k_layer. R13 lesson: quadrant ordering helps k_layer slightly but its
// passB cost exceeds the gain (cohort drift); reverted. This round: byte-exact
// R10 build + epilogue, k_layer software-pipelines the only serial inter-step
// dependency (the 16-edge packed batch load) under the 16-product body.
// Numerics bitwise-identical to R10: unbiased __float2int_rn at scale 2^27,
// int32 sums order-independent -> identical graph replays.
//   build: bcount (196-bin hist) -> bscan -> passA (two-level cursor scatter,
//          PRESCALED vals) -> passB (per-bucket LDS hist+scan -> row_ptr + CSR)
//   per t: 16-lane group per row; LDS edge broadcast; int32-rn accumulate.
//   final: planes[t][n][b] -> out[b][n][t]

#define N_NEURONS 100000
#define NNZ_CNT   3200000
#define N_SENSORY 5000
#define BATCH     16
#define T_LAYERS  8
#define THRESH    0.01f
#define STEEP     5.0f

#define NB (N_NEURONS * BATCH)
#define NT (N_NEURONS * T_LAYERS)
#define ST (N_SENSORY * T_LAYERS)

#define FXS32     134217728.0f             /* 2^27: exact fp32 prescale */
#define FXI32     7.450580596923828e-9f    /* 2^-27 exact */

#define LBITS   9
#define BROWS   (1 << LBITS)                           /* 512 rows per bucket */
#define NBUCKET ((N_NEURONS + BROWS - 1) / BROWS)      /* 196 */
#define EPB     4096                                   /* edges per build block */
#define NBLK_A  ((NNZ_CNT + EPB - 1) / EPB)            /* 782 */

#define FXSCALE   17592186044416.0f        /* fallback path only (2^44) */
#define FXINV     (1.0 / 17592186044416.0)

__device__ __forceinline__ float thresh_clamp_inp(float u) {
    u = (u >= THRESH) ? u : 0.0f;
    return fminf(u, 1.0f);
}
__device__ __forceinline__ float activate(float y) {
    y = (y >= THRESH) ? y : 0.0f;
    return tanhf(STEEP * y);
}

// ---------------- build (byte-identical to R10) ----------------

__global__ void k_init(const float* __restrict__ inp, float* __restrict__ state0,
                       int* __restrict__ btotal) {
    int i = blockIdx.x * blockDim.x + threadIdx.x;
    if (i >= NB) return;
    int n = i >> 4, b = i & 15;
    float v = 0.0f;
    if (n < N_SENSORY) v = thresh_clamp_inp(inp[b * ST + n * T_LAYERS + 0]);
    state0[i] = v;
    if (i < NBUCKET) btotal[i] = 0;
}

__global__ void __launch_bounds__(1024) k_bcount(const int* __restrict__ rows,
                                                 int* __restrict__ btotal) {
    __shared__ int cnt[NBUCKET];
    const int e0 = blockIdx.x * EPB;
    for (int i = threadIdx.x; i < NBUCKET; i += 1024) cnt[i] = 0;
    __syncthreads();
    #pragma unroll
    for (int i = 0; i < EPB / 1024; ++i) {
        int e = e0 + i * 1024 + threadIdx.x;
        if (e < NNZ_CNT) atomicAdd(&cnt[rows[e] >> LBITS], 1);
    }
    __syncthreads();
    for (int i = threadIdx.x; i < NBUCKET; i += 1024)
        if (cnt[i]) atomicAdd(&btotal[i], cnt[i]);
}

__global__ void k_bscan(const int* __restrict__ btotal, int* __restrict__ bbase,
                        int* __restrict__ bcur, int* __restrict__ row_ptr) {
    __shared__ int lds[256];
    int tid = threadIdx.x;
    int v = (tid < NBUCKET) ? btotal[tid] : 0;
    lds[tid] = v;
    __syncthreads();
    for (int off = 1; off < 256; off <<= 1) {
        int add = (tid >= off) ? lds[tid - off] : 0;
        __syncthreads();
        lds[tid] += add;
        __syncthreads();
    }
    if (tid < NBUCKET) {
        bbase[tid] = lds[tid] - v;
        bcur[tid]  = lds[tid] - v;
    }
    if (tid == 0) { bbase[NBUCKET] = NNZ_CNT; row_ptr[N_NEURONS] = NNZ_CNT; }
}

__global__ void __launch_bounds__(1024) k_passA(const float* __restrict__ vals,
                                                const int* __restrict__ rows,
                                                const int* __restrict__ cols,
                                                int* bcur,
                                                int2* __restrict__ slab) {
    __shared__ int cnt[NBUCKET];
    __shared__ int base[NBUCKET];
    const int e0 = blockIdx.x * EPB;
    for (int i = threadIdx.x; i < NBUCKET; i += 1024) cnt[i] = 0;
    __syncthreads();
    #pragma unroll
    for (int i = 0; i < EPB / 1024; ++i) {
        int e = e0 + i * 1024 + threadIdx.x;
        if (e < NNZ_CNT) atomicAdd(&cnt[rows[e] >> LBITS], 1);
    }
    __syncthreads();
    for (int i = threadIdx.x; i < NBUCKET; i += 1024) {
        int c = cnt[i];
        base[i] = (c > 0) ? atomicAdd(&bcur[i], c) : 0;
        cnt[i] = 0;
    }
    __syncthreads();
    #pragma unroll
    for (int i = 0; i < EPB / 1024; ++i) {
        int e = e0 + i * 1024 + threadIdx.x;
        if (e < NNZ_CNT) {
            int r = rows[e];
            int k = r >> LBITS;
            int pos = base[k] + atomicAdd(&cnt[k], 1);
            slab[pos] = make_int2((cols[e] << LBITS) | (r & (BROWS - 1)),
                                  __float_as_int(vals[e] * FXS32));   // exact prescale
        }
    }
}

__global__ void __launch_bounds__(1024) k_passB(const int* __restrict__ bbase,
                                                const int2* __restrict__ slab,
                                                int2* __restrict__ packed,
                                                int* __restrict__ row_ptr) {
    __shared__ int cnt[BROWS];
    __shared__ int scn[BROWS];
    const int tid = threadIdx.x;
    const int k  = blockIdx.x;
    const int r0 = k * BROWS;
    const int nr = min(BROWS, N_NEURONS - r0);
    const int P0 = bbase[k], P1 = bbase[k + 1];
    for (int i = tid; i < BROWS; i += 1024) cnt[i] = 0;
    __syncthreads();
    for (int i = P0 + tid; i < P1; i += 1024)
        atomicAdd(&cnt[slab[i].x & (BROWS - 1)], 1);
    __syncthreads();
    if (tid < BROWS) scn[tid] = cnt[tid];
    __syncthreads();
    for (int off = 1; off < BROWS; off <<= 1) {
        int add = (tid < BROWS && tid >= off) ? scn[tid - off] : 0;
        __syncthreads();
        if (tid < BROWS) scn[tid] += add;
        __syncthreads();
    }
    if (tid < BROWS) {
        int ex = P0 + scn[tid] - cnt[tid];      // exclusive row base
        if (tid < nr) row_ptr[r0 + tid] = ex;
        scn[tid] = ex;                          // cursor
    }
    __syncthreads();
    for (int i = P0 + tid; i < P1; i += 1024) {
        int2 pe = slab[i];
        int d = atomicAdd(&scn[pe.x & (BROWS - 1)], 1);
        packed[d] = make_int2(pe.x >> LBITS, pe.y);   // (col, prescaled val)
    }
}

// ---------------- fused per-layer SpMM + activation ----------------
// R10 shape + packed-stream prefetch: the 16-edge batch for step k+1 is loaded
// while step k's LDS staging + 16 products execute (the only serial inter-step
// dependency). 16-lane group per row; LDS same-address broadcast; int32-rn acc.
__global__ void __launch_bounds__(256) k_layer(const int* __restrict__ row_ptr,
                                               const int2* __restrict__ packed,
                                               const float* __restrict__ state_in,
                                               const float* __restrict__ inp,
                                               float* __restrict__ plane_out,
                                               int t) {
    __shared__ int2 ebuf[16][17];               // [group][slot], +1 pad
    const int tid = threadIdx.x;
    const int g = tid >> 4, b = tid & 15;
    const int r = blockIdx.x * 16 + g;          // 6250*16 == N_NEURONS exactly
    const int s = row_ptr[r], e = row_ptr[r + 1];
    int acc = 0;
    int idx0 = s + b;
    int2 pe = (idx0 < e) ? packed[idx0] : make_int2(0, 0);
    for (int base = s; base < e; base += 16) {
        int nidx = base + 16 + b;               // prefetch next batch NOW
        int2 pe_next = (nidx < e) ? packed[nidx] : make_int2(0, 0);
        ebuf[g][b] = pe;                        // wave-lockstep, in-order DS pipe
        #pragma unroll
        for (int j = 0; j < 16; ++j) {
            int2 q = ebuf[g][j];                // 16-lane same-address broadcast read
            float prod = __int_as_float(q.y) * state_in[q.x * BATCH + b];
            acc += __float2int_rn(prod);        // UNBIASED quantization at 2^-28
        }
        pe = pe_next;
    }
    float y = (float)acc * FXI32;
    float a = activate(y);
    if (t < T_LAYERS - 1) {
        if (r < N_SENSORY) a += thresh_clamp_inp(inp[b * ST + r * T_LAYERS + (t + 1)]);
        a = fminf(a, 1.0f);                     // off-sensory no-op (|tanh|<1)
    }
    plane_out[r * BATCH + b] = a;
}

// ---------------- planes[t][n][b] -> out[b][n][t] ----------------
__global__ void k_out(const float* __restrict__ planes, float* __restrict__ out) {
    int i = blockIdx.x * blockDim.x + threadIdx.x;
    if (i >= NB) return;
    int n = i >> 4, b = i & 15;
    float4 o0, o1;
    o0.x = planes[0 * NB + i]; o0.y = planes[1 * NB + i];
    o0.z = planes[2 * NB + i]; o0.w = planes[3 * NB + i];
    o1.x = planes[4 * NB + i]; o1.y = planes[5 * NB + i];
    o1.z = planes[6 * NB + i]; o1.w = planes[7 * NB + i];
    float4* dst = (float4*)&out[b * NT + n * T_LAYERS];
    dst[0] = o0; dst[1] = o1;
}

// ---------------- fallback (atomic fixed-point path, 19.2 MB ws) ----------------
__global__ void k2_init(const float* __restrict__ inp, float* __restrict__ state,
                        long long* __restrict__ acc) {
    int stride = gridDim.x * blockDim.x;
    for (int i = blockIdx.x * blockDim.x + threadIdx.x; i < NB; i += stride) {
        int n = i >> 4, b = i & 15;
        float v = 0.0f;
        if (n < N_SENSORY) v = thresh_clamp_inp(inp[b * ST + n * T_LAYERS + 0]);
        state[i] = v;
        acc[i]   = 0LL;
    }
}
__global__ void __launch_bounds__(256) k2_spmm(const float* __restrict__ vals,
                                               const int* __restrict__ rows,
                                               const int* __restrict__ cols,
                                               const float* __restrict__ state,
                                               long long* acc) {
    int tid = blockIdx.x * blockDim.x + threadIdx.x;
    int b = tid & 15;
    int e = tid >> 4;
    int estride = (gridDim.x * blockDim.x) >> 4;
    for (; e < NNZ_CNT; e += estride) {
        float xv = state[cols[e] * BATCH + b];
        long long fx = llrintf(vals[e] * xv * FXSCALE);
        if (fx != 0LL)
            atomicAdd((unsigned long long*)&acc[rows[e] * BATCH + b], (unsigned long long)fx);
    }
}
__global__ void k2_act_inject(long long* acc, const float* __restrict__ inp,
                              float* __restrict__ state, float* __restrict__ out, int t) {
    int stride = gridDim.x * blockDim.x;
    for (int i = blockIdx.x * blockDim.x + threadIdx.x; i < NB; i += stride) {
        int n = i >> 4, b = i & 15;
        float y = (float)((double)acc[i] * FXINV);
        acc[i] = 0LL;
        float v = activate(y);
        if (n < N_SENSORY) v += thresh_clamp_inp(inp[b * ST + n * T_LAYERS + (t + 1)]);
        v = fminf(v, 1.0f);
        state[i] = v;
        out[b * NT + n * T_LAYERS + t] = v;
    }
}
__global__ void k2_act_final(const long long* __restrict__ acc, float* __restrict__ out) {
    int stride = gridDim.x * blockDim.x;
    for (int i = blockIdx.x * blockDim.x + threadIdx.x; i < NB; i += stride) {
        int n = i >> 4, b = i & 15;
        float y = (float)((double)acc[i] * FXINV);
        out[b * NT + n * T_LAYERS + (T_LAYERS - 1)] = activate(y);
    }
}

extern "C" void kernel_launch(void* const* d_in, const int* in_sizes, int n_in,
                              void* d_out, int out_size, void* d_ws, size_t ws_size,
                              hipStream_t stream) {
    const float* inputs = (const float*)d_in[0];
    const float* vals   = (const float*)d_in[1];
    const int*   rows   = (const int*)  d_in[2];
    const int*   cols   = (const int*)  d_in[3];
    float* out = (float*)d_out;

    const size_t sz_planes = (size_t)T_LAYERS * NB * 4;   // 51.2 MB
    const size_t sz_packed = (size_t)NNZ_CNT * 8;         // 25.6 MB
    const size_t sz_rowptr = ((size_t)N_NEURONS + 2) * 4;
    const size_t sz_bt     = (size_t)(NBUCKET + 8) * 4;
    const size_t REQ = sz_planes + sz_packed + sz_rowptr + 3 * sz_bt;

    const int block = 256;

    if (ws_size >= REQ) {
        char* ws = (char*)d_ws;
        float* planes  = (float*)ws;
        int2*  packed  = (int2*)(ws + sz_planes);
        int*   row_ptr = (int*)(ws + sz_planes + sz_packed);
        int*   btotal  = (int*)(ws + sz_planes + sz_packed + sz_rowptr);
        int*   bbase   = (int*)(ws + sz_planes + sz_packed + sz_rowptr + sz_bt);
        int*   bcur    = (int*)(ws + sz_planes + sz_packed + sz_rowptr + 2 * sz_bt);
        float* state0  = planes + (size_t)(T_LAYERS - 1) * NB;  // planes[7], consumed at t=0
        int2*  slab    = (int2*)planes;   // build scratch aliases planes[0..3]; dead before layers

        const int grid_nb = (NB + block - 1) / block;           // 6250

        k_init<<<grid_nb, block, 0, stream>>>(inputs, state0, btotal);
        k_bcount<<<NBLK_A, 1024, 0, stream>>>(rows, btotal);
        k_bscan<<<1, 256, 0, stream>>>(btotal, bbase, bcur, row_ptr);
        k_passA<<<NBLK_A, 1024, 0, stream>>>(vals, rows, cols, bcur, slab);
        k_passB<<<NBUCKET, 1024, 0, stream>>>(bbase, slab, packed, row_ptr);

        for (int t = 0; t < T_LAYERS; ++t) {
            const float* sin_ = (t == 0) ? state0 : planes + (size_t)(t - 1) * NB;
            k_layer<<<grid_nb, block, 0, stream>>>(row_ptr, packed, sin_, inputs,
                                                   planes + (size_t)t * NB, t);
        }
        k_out<<<grid_nb, block, 0, stream>>>(planes, out);
    } else {
        long long* acc   = (long long*)d_ws;
        float*     state = (float*)(acc + NB);
        const int grid_ew = 2048, grid_sp = 2048;
        k2_init<<<grid_ew, block, 0, stream>>>(inputs, state, acc);
        for (int t = 0; t < T_LAYERS; ++t) {
            k2_spmm<<<grid_sp, block, 0, stream>>>(vals, rows, cols, state, acc);
            if (t < T_LAYERS - 1)
                k2_act_inject<<<grid_ew, block, 0, stream>>>(acc, inputs, state, out, t);
            else
                k2_act_final<<<grid_ew, block, 0, stream>>>(acc, out);
        }
    }
}

// Round 15
// 378.940 us; speedup vs baseline: 1.5273x; 1.0052x over previous
//
#include <hip/hip_runtime.h>

// MultilayeredNetwork v13 = R14 (381us) with leaner build:
//  - k_bcount/btotal DELETED: fixed-capacity bucket slabs (CAP = mean+16sigma,
//    data is fixed seed -> counts are constants; overflow prob ~1e-60).
//    bcur[k] = k*CAP set in k_init; tiny post-passA scan recovers exact counts.
//  - k_passA at 512 threads (EPB 2048): 4 barrier-pipelines/CU instead of 2
//    (passA is phase-barrier-latency bound, not BW bound: 2.7% VALU, 4.7% HBM).
// k_layer byte-identical to R14 (prefetch, 16-lane group, LDS broadcast,
// unbiased __float2int_rn @2^27). Numerics bitwise-identical; int32 sums
// order-independent -> identical graph replays. absmax floor 0.00390625 (bf16
// ref-comparison quantum).

#define N_NEURONS 100000
#define NNZ_CNT   3200000
#define N_SENSORY 5000
#define BATCH     16
#define T_LAYERS  8
#define THRESH    0.01f
#define STEEP     5.0f

#define NB (N_NEURONS * BATCH)
#define NT (N_NEURONS * T_LAYERS)
#define ST (N_SENSORY * T_LAYERS)

#define FXS32     134217728.0f             /* 2^27: exact fp32 prescale */
#define FXI32     7.450580596923828e-9f    /* 2^-27 exact */

#define LBITS   9
#define BROWS   (1 << LBITS)                           /* 512 rows per bucket */
#define NBUCKET ((N_NEURONS + BROWS - 1) / BROWS)      /* 196 */
#define BCAP    18432                                  /* bucket slab capacity (mean 16327 + 16sigma) */
#define EPB     2048                                   /* edges per passA block */
#define NBLK_A  ((NNZ_CNT + EPB - 1) / EPB)            /* 1563 */

#define FXSCALE   17592186044416.0f        /* fallback path only (2^44) */
#define FXINV     (1.0 / 17592186044416.0)

__device__ __forceinline__ float thresh_clamp_inp(float u) {
    u = (u >= THRESH) ? u : 0.0f;
    return fminf(u, 1.0f);
}
__device__ __forceinline__ float activate(float y) {
    y = (y >= THRESH) ? y : 0.0f;
    return tanhf(STEEP * y);
}

// ---------------- build ----------------

// state0 (planes[7] slot) + fixed-capacity bucket cursors.
__global__ void k_init(const float* __restrict__ inp, float* __restrict__ state0,
                       int* __restrict__ bcur) {
    int i = blockIdx.x * blockDim.x + threadIdx.x;
    if (i >= NB) return;
    int n = i >> 4, b = i & 15;
    float v = 0.0f;
    if (n < N_SENSORY) v = thresh_clamp_inp(inp[b * ST + n * T_LAYERS + 0]);
    state0[i] = v;
    if (i < NBUCKET) bcur[i] = i * BCAP;
}

// pass A: two-level scatter into FIXED-CAPACITY bucket slabs. Block bins EPB
// edges in LDS, bulk-reserves (ONE global atomic per bucket per block), places.
// lo word packs (col << 9) | (row & 511); hi word = PRESCALED (2^27) val bits.
__global__ void __launch_bounds__(512) k_passA(const float* __restrict__ vals,
                                               const int* __restrict__ rows,
                                               const int* __restrict__ cols,
                                               int* bcur,
                                               int2* __restrict__ slab) {
    __shared__ int cnt[NBUCKET];
    __shared__ int base[NBUCKET];
    const int e0 = blockIdx.x * EPB;
    for (int i = threadIdx.x; i < NBUCKET; i += 512) cnt[i] = 0;
    __syncthreads();
    #pragma unroll
    for (int i = 0; i < EPB / 512; ++i) {
        int e = e0 + i * 512 + threadIdx.x;
        if (e < NNZ_CNT) atomicAdd(&cnt[rows[e] >> LBITS], 1);
    }
    __syncthreads();
    for (int i = threadIdx.x; i < NBUCKET; i += 512) {
        int c = cnt[i];
        base[i] = (c > 0) ? atomicAdd(&bcur[i], c) : 0;
        cnt[i] = 0;
    }
    __syncthreads();
    #pragma unroll
    for (int i = 0; i < EPB / 512; ++i) {
        int e = e0 + i * 512 + threadIdx.x;
        if (e < NNZ_CNT) {
            int r = rows[e];
            int k = r >> LBITS;
            int pos = base[k] + atomicAdd(&cnt[k], 1);
            slab[pos] = make_int2((cols[e] << LBITS) | (r & (BROWS - 1)),
                                  __float_as_int(vals[e] * FXS32));   // exact prescale
        }
    }
}

// post-passA: exact bucket counts (bcur[k]-k*BCAP) -> tight exclusive bases.
__global__ void k_bscan2(const int* __restrict__ bcur, int* __restrict__ bbase,
                         int* __restrict__ row_ptr) {
    __shared__ int lds[256];
    int tid = threadIdx.x;
    int c = (tid < NBUCKET) ? (bcur[tid] - tid * BCAP) : 0;
    lds[tid] = c;
    __syncthreads();
    for (int off = 1; off < 256; off <<= 1) {
        int add = (tid >= off) ? lds[tid - off] : 0;
        __syncthreads();
        lds[tid] += add;
        __syncthreads();
    }
    if (tid < NBUCKET) bbase[tid] = lds[tid] - c;   // tight base into packed
    if (tid == 0) { bbase[NBUCKET] = NNZ_CNT; row_ptr[N_NEURONS] = NNZ_CNT; }
}

// pass B: per-bucket slab (fixed-cap region) -> LDS row histogram + scan ->
// row_ptr AND final tight CSR scatter.
__global__ void __launch_bounds__(1024) k_passB(const int* __restrict__ bcur,
                                                const int* __restrict__ bbase,
                                                const int2* __restrict__ slab,
                                                int2* __restrict__ packed,
                                                int* __restrict__ row_ptr) {
    __shared__ int cnt[BROWS];
    __shared__ int scn[BROWS];
    const int tid = threadIdx.x;
    const int k  = blockIdx.x;
    const int r0 = k * BROWS;
    const int nr = min(BROWS, N_NEURONS - r0);
    const int S0 = k * BCAP;                       // slab region
    const int SC = bcur[k] - S0;                   // exact bucket count
    const int Q0 = bbase[k];                       // tight packed base
    for (int i = tid; i < BROWS; i += 1024) cnt[i] = 0;
    __syncthreads();
    for (int i = tid; i < SC; i += 1024)
        atomicAdd(&cnt[slab[S0 + i].x & (BROWS - 1)], 1);
    __syncthreads();
    if (tid < BROWS) scn[tid] = cnt[tid];
    __syncthreads();
    for (int off = 1; off < BROWS; off <<= 1) {
        int add = (tid < BROWS && tid >= off) ? scn[tid - off] : 0;
        __syncthreads();
        if (tid < BROWS) scn[tid] += add;
        __syncthreads();
    }
    if (tid < BROWS) {
        int ex = Q0 + scn[tid] - cnt[tid];          // exclusive row base (tight)
        if (tid < nr) row_ptr[r0 + tid] = ex;
        scn[tid] = ex;                              // cursor
    }
    __syncthreads();
    for (int i = tid; i < SC; i += 1024) {
        int2 pe = slab[S0 + i];
        int d = atomicAdd(&scn[pe.x & (BROWS - 1)], 1);
        packed[d] = make_int2(pe.x >> LBITS, pe.y); // (col, prescaled val)
    }
}

// ---------------- fused per-layer SpMM + activation (byte-identical to R14) ----------------
__global__ void __launch_bounds__(256) k_layer(const int* __restrict__ row_ptr,
                                               const int2* __restrict__ packed,
                                               const float* __restrict__ state_in,
                                               const float* __restrict__ inp,
                                               float* __restrict__ plane_out,
                                               int t) {
    __shared__ int2 ebuf[16][17];               // [group][slot], +1 pad
    const int tid = threadIdx.x;
    const int g = tid >> 4, b = tid & 15;
    const int r = blockIdx.x * 16 + g;          // 6250*16 == N_NEURONS exactly
    const int s = row_ptr[r], e = row_ptr[r + 1];
    int acc = 0;
    int idx0 = s + b;
    int2 pe = (idx0 < e) ? packed[idx0] : make_int2(0, 0);
    for (int base = s; base < e; base += 16) {
        int nidx = base + 16 + b;               // prefetch next batch NOW
        int2 pe_next = (nidx < e) ? packed[nidx] : make_int2(0, 0);
        ebuf[g][b] = pe;                        // wave-lockstep, in-order DS pipe
        #pragma unroll
        for (int j = 0; j < 16; ++j) {
            int2 q = ebuf[g][j];                // 16-lane same-address broadcast read
            float prod = __int_as_float(q.y) * state_in[q.x * BATCH + b];
            acc += __float2int_rn(prod);        // UNBIASED quantization at 2^-28
        }
        pe = pe_next;
    }
    float y = (float)acc * FXI32;
    float a = activate(y);
    if (t < T_LAYERS - 1) {
        if (r < N_SENSORY) a += thresh_clamp_inp(inp[b * ST + r * T_LAYERS + (t + 1)]);
        a = fminf(a, 1.0f);                     // off-sensory no-op (|tanh|<1)
    }
    plane_out[r * BATCH + b] = a;
}

// ---------------- planes[t][n][b] -> out[b][n][t] ----------------
__global__ void k_out(const float* __restrict__ planes, float* __restrict__ out) {
    int i = blockIdx.x * blockDim.x + threadIdx.x;
    if (i >= NB) return;
    int n = i >> 4, b = i & 15;
    float4 o0, o1;
    o0.x = planes[0 * NB + i]; o0.y = planes[1 * NB + i];
    o0.z = planes[2 * NB + i]; o0.w = planes[3 * NB + i];
    o1.x = planes[4 * NB + i]; o1.y = planes[5 * NB + i];
    o1.z = planes[6 * NB + i]; o1.w = planes[7 * NB + i];
    float4* dst = (float4*)&out[b * NT + n * T_LAYERS];
    dst[0] = o0; dst[1] = o1;
}

// ---------------- fallback (atomic fixed-point path, 19.2 MB ws) ----------------
__global__ void k2_init(const float* __restrict__ inp, float* __restrict__ state,
                        long long* __restrict__ acc) {
    int stride = gridDim.x * blockDim.x;
    for (int i = blockIdx.x * blockDim.x + threadIdx.x; i < NB; i += stride) {
        int n = i >> 4, b = i & 15;
        float v = 0.0f;
        if (n < N_SENSORY) v = thresh_clamp_inp(inp[b * ST + n * T_LAYERS + 0]);
        state[i] = v;
        acc[i]   = 0LL;
    }
}
__global__ void __launch_bounds__(256) k2_spmm(const float* __restrict__ vals,
                                               const int* __restrict__ rows,
                                               const int* __restrict__ cols,
                                               const float* __restrict__ state,
                                               long long* acc) {
    int tid = blockIdx.x * blockDim.x + threadIdx.x;
    int b = tid & 15;
    int e = tid >> 4;
    int estride = (gridDim.x * blockDim.x) >> 4;
    for (; e < NNZ_CNT; e += estride) {
        float xv = state[cols[e] * BATCH + b];
        long long fx = llrintf(vals[e] * xv * FXSCALE);
        if (fx != 0LL)
            atomicAdd((unsigned long long*)&acc[rows[e] * BATCH + b], (unsigned long long)fx);
    }
}
__global__ void k2_act_inject(long long* acc, const float* __restrict__ inp,
                              float* __restrict__ state, float* __restrict__ out, int t) {
    int stride = gridDim.x * blockDim.x;
    for (int i = blockIdx.x * blockDim.x + threadIdx.x; i < NB; i += stride) {
        int n = i >> 4, b = i & 15;
        float y = (float)((double)acc[i] * FXINV);
        acc[i] = 0LL;
        float v = activate(y);
        if (n < N_SENSORY) v += thresh_clamp_inp(inp[b * ST + n * T_LAYERS + (t + 1)]);
        v = fminf(v, 1.0f);
        state[i] = v;
        out[b * NT + n * T_LAYERS + t] = v;
    }
}
__global__ void k2_act_final(const long long* __restrict__ acc, float* __restrict__ out) {
    int stride = gridDim.x * blockDim.x;
    for (int i = blockIdx.x * blockDim.x + threadIdx.x; i < NB; i += stride) {
        int n = i >> 4, b = i & 15;
        float y = (float)((double)acc[i] * FXINV);
        out[b * NT + n * T_LAYERS + (T_LAYERS - 1)] = activate(y);
    }
}

extern "C" void kernel_launch(void* const* d_in, const int* in_sizes, int n_in,
                              void* d_out, int out_size, void* d_ws, size_t ws_size,
                              hipStream_t stream) {
    const float* inputs = (const float*)d_in[0];
    const float* vals   = (const float*)d_in[1];
    const int*   rows   = (const int*)  d_in[2];
    const int*   cols   = (const int*)  d_in[3];
    float* out = (float*)d_out;

    const size_t sz_planes = (size_t)T_LAYERS * NB * 4;   // 51.2 MB (slab 28.9MB aliases planes[0..4])
    const size_t sz_packed = (size_t)NNZ_CNT * 8;         // 25.6 MB
    const size_t sz_rowptr = ((size_t)N_NEURONS + 2) * 4;
    const size_t sz_bt     = (size_t)(NBUCKET + 8) * 4;
    const size_t REQ = sz_planes + sz_packed + sz_rowptr + 2 * sz_bt;

    const int block = 256;

    if (ws_size >= REQ) {
        char* ws = (char*)d_ws;
        float* planes  = (float*)ws;
        int2*  packed  = (int2*)(ws + sz_planes);
        int*   row_ptr = (int*)(ws + sz_planes + sz_packed);
        int*   bbase   = (int*)(ws + sz_planes + sz_packed + sz_rowptr);
        int*   bcur    = (int*)(ws + sz_planes + sz_packed + sz_rowptr + sz_bt);
        float* state0  = planes + (size_t)(T_LAYERS - 1) * NB;  // planes[7], consumed at t=0
        int2*  slab    = (int2*)planes;   // 28.9 MB build scratch; dead before layers

        const int grid_nb = (NB + block - 1) / block;           // 6250

        k_init<<<grid_nb, block, 0, stream>>>(inputs, state0, bcur);
        k_passA<<<NBLK_A, 512, 0, stream>>>(vals, rows, cols, bcur, slab);
        k_bscan2<<<1, 256, 0, stream>>>(bcur, bbase, row_ptr);
        k_passB<<<NBUCKET, 1024, 0, stream>>>(bcur, bbase, slab, packed, row_ptr);

        for (int t = 0; t < T_LAYERS; ++t) {
            const float* sin_ = (t == 0) ? state0 : planes + (size_t)(t - 1) * NB;
            k_layer<<<grid_nb, block, 0, stream>>>(row_ptr, packed, sin_, inputs,
                                                   planes + (size_t)t * NB, t);
        }
        k_out<<<grid_nb, block, 0, stream>>>(planes, out);
    } else {
        long long* acc   = (long long*)d_ws;
        float*     state = (float*)(acc + NB);
        const int grid_ew = 2048, grid_sp = 2048;
        k2_init<<<grid_ew, block, 0, stream>>>(inputs, state, acc);
        for (int t = 0; t < T_LAYERS; ++t) {
            k2_spmm<<<grid_sp, block, 0, stream>>>(vals, rows, cols, state, acc);
            if (t < T_LAYERS - 1)
                k2_act_inject<<<grid_ew, block, 0, stream>>>(acc, inputs, state, out, t);
            else
                k2_act_final<<<grid_ew, block, 0, stream>>>(acc, out);
        }
    }
}

// Round 16
// 360.056 us; speedup vs baseline: 1.6074x; 1.0524x over previous
//
#include <hip/hip_runtime.h>

// MultilayeredNetwork v14 = R15 build structure (no bcount; fixed-cap slabs;
// bscan2; passB tight-scatter) + passA restored to 1024thr/EPB4096 with 4-WAY
// REPLICATED LDS counters. R15 lesson: passA is bound by per-block overhead +
// LDS-atomic serialization (bank-conflict 711K, pinned), NOT barrier pipelining.
// Quarter q=tid>>8 counts into cnt[q][bin]; reserve sums replicas (one global
// atomic per bucket, as before) and derives per-quarter bases; place phase uses
// its quarter's cursor -> ~4x fewer colliding writers per LDS address.
// Within-bucket placement order changes: harmless (int32 fixed-point sums are
// order-independent -> bitwise-identical graph replays).
// k_layer byte-identical to R14/R15 best (prefetch + LDS broadcast + rn@2^27).

#define N_NEURONS 100000
#define NNZ_CNT   3200000
#define N_SENSORY 5000
#define BATCH     16
#define T_LAYERS  8
#define THRESH    0.01f
#define STEEP     5.0f

#define NB (N_NEURONS * BATCH)
#define NT (N_NEURONS * T_LAYERS)
#define ST (N_SENSORY * T_LAYERS)

#define FXS32     134217728.0f             /* 2^27: exact fp32 prescale */
#define FXI32     7.450580596923828e-9f    /* 2^-27 exact */

#define LBITS   9
#define BROWS   (1 << LBITS)                           /* 512 rows per bucket */
#define NBUCKET ((N_NEURONS + BROWS - 1) / BROWS)      /* 196 */
#define BCAP    18432                                  /* bucket slab cap (mean 16327 + 16sigma) */
#define EPB     4096                                   /* edges per passA block */
#define NBLK_A  ((NNZ_CNT + EPB - 1) / EPB)            /* 782 */

#define FXSCALE   17592186044416.0f        /* fallback path only (2^44) */
#define FXINV     (1.0 / 17592186044416.0)

__device__ __forceinline__ float thresh_clamp_inp(float u) {
    u = (u >= THRESH) ? u : 0.0f;
    return fminf(u, 1.0f);
}
__device__ __forceinline__ float activate(float y) {
    y = (y >= THRESH) ? y : 0.0f;
    return tanhf(STEEP * y);
}

// ---------------- build ----------------

// state0 (planes[7] slot) + fixed-capacity bucket cursors.
__global__ void k_init(const float* __restrict__ inp, float* __restrict__ state0,
                       int* __restrict__ bcur) {
    int i = blockIdx.x * blockDim.x + threadIdx.x;
    if (i >= NB) return;
    int n = i >> 4, b = i & 15;
    float v = 0.0f;
    if (n < N_SENSORY) v = thresh_clamp_inp(inp[b * ST + n * T_LAYERS + 0]);
    state0[i] = v;
    if (i < NBUCKET) bcur[i] = i * BCAP;
}

// pass A: two-level scatter into fixed-capacity bucket slabs, 4-way replicated
// LDS counters (quarter = tid>>8). lo word packs (col<<9)|(row&511);
// hi word = PRESCALED (2^27) val bits.
__global__ void __launch_bounds__(1024) k_passA(const float* __restrict__ vals,
                                                const int* __restrict__ rows,
                                                const int* __restrict__ cols,
                                                int* bcur,
                                                int2* __restrict__ slab) {
    __shared__ int cnt[4][NBUCKET];
    __shared__ int base[4][NBUCKET];
    const int e0 = blockIdx.x * EPB;
    const int q  = threadIdx.x >> 8;            // quarter 0..3
    for (int i = threadIdx.x; i < 4 * NBUCKET; i += 1024) (&cnt[0][0])[i] = 0;
    __syncthreads();
    // phase 1: count (per-quarter replica)
    #pragma unroll
    for (int i = 0; i < EPB / 1024; ++i) {
        int e = e0 + i * 1024 + threadIdx.x;
        if (e < NNZ_CNT) atomicAdd(&cnt[q][rows[e] >> LBITS], 1);
    }
    __syncthreads();
    // phase 2: bulk reserve (one global atomic per bucket) + per-quarter bases
    for (int i = threadIdx.x; i < NBUCKET; i += 1024) {
        int c0 = cnt[0][i], c1 = cnt[1][i], c2 = cnt[2][i], c3 = cnt[3][i];
        int tot = c0 + c1 + c2 + c3;
        int g = (tot > 0) ? atomicAdd(&bcur[i], tot) : 0;
        base[0][i] = g;
        base[1][i] = g + c0;
        base[2][i] = g + c0 + c1;
        base[3][i] = g + c0 + c1 + c2;
        cnt[0][i] = 0; cnt[1][i] = 0; cnt[2][i] = 0; cnt[3][i] = 0;
    }
    __syncthreads();
    // phase 3: place (per-quarter cursor)
    #pragma unroll
    for (int i = 0; i < EPB / 1024; ++i) {
        int e = e0 + i * 1024 + threadIdx.x;
        if (e < NNZ_CNT) {
            int r = rows[e];
            int k = r >> LBITS;
            int pos = base[q][k] + atomicAdd(&cnt[q][k], 1);
            slab[pos] = make_int2((cols[e] << LBITS) | (r & (BROWS - 1)),
                                  __float_as_int(vals[e] * FXS32));   // exact prescale
        }
    }
}

// post-passA: exact bucket counts (bcur[k]-k*BCAP) -> tight exclusive bases.
__global__ void k_bscan2(const int* __restrict__ bcur, int* __restrict__ bbase,
                         int* __restrict__ row_ptr) {
    __shared__ int lds[256];
    int tid = threadIdx.x;
    int c = (tid < NBUCKET) ? (bcur[tid] - tid * BCAP) : 0;
    lds[tid] = c;
    __syncthreads();
    for (int off = 1; off < 256; off <<= 1) {
        int add = (tid >= off) ? lds[tid - off] : 0;
        __syncthreads();
        lds[tid] += add;
        __syncthreads();
    }
    if (tid < NBUCKET) bbase[tid] = lds[tid] - c;   // tight base into packed
    if (tid == 0) { bbase[NBUCKET] = NNZ_CNT; row_ptr[N_NEURONS] = NNZ_CNT; }
}

// pass B: per-bucket slab region -> LDS row histogram + scan -> row_ptr AND
// final tight CSR scatter.
__global__ void __launch_bounds__(1024) k_passB(const int* __restrict__ bcur,
                                                const int* __restrict__ bbase,
                                                const int2* __restrict__ slab,
                                                int2* __restrict__ packed,
                                                int* __restrict__ row_ptr) {
    __shared__ int cnt[BROWS];
    __shared__ int scn[BROWS];
    const int tid = threadIdx.x;
    const int k  = blockIdx.x;
    const int r0 = k * BROWS;
    const int nr = min(BROWS, N_NEURONS - r0);
    const int S0 = k * BCAP;                       // slab region
    const int SC = bcur[k] - S0;                   // exact bucket count
    const int Q0 = bbase[k];                       // tight packed base
    for (int i = tid; i < BROWS; i += 1024) cnt[i] = 0;
    __syncthreads();
    for (int i = tid; i < SC; i += 1024)
        atomicAdd(&cnt[slab[S0 + i].x & (BROWS - 1)], 1);
    __syncthreads();
    if (tid < BROWS) scn[tid] = cnt[tid];
    __syncthreads();
    for (int off = 1; off < BROWS; off <<= 1) {
        int add = (tid < BROWS && tid >= off) ? scn[tid - off] : 0;
        __syncthreads();
        if (tid < BROWS) scn[tid] += add;
        __syncthreads();
    }
    if (tid < BROWS) {
        int ex = Q0 + scn[tid] - cnt[tid];          // exclusive row base (tight)
        if (tid < nr) row_ptr[r0 + tid] = ex;
        scn[tid] = ex;                              // cursor
    }
    __syncthreads();
    for (int i = tid; i < SC; i += 1024) {
        int2 pe = slab[S0 + i];
        int d = atomicAdd(&scn[pe.x & (BROWS - 1)], 1);
        packed[d] = make_int2(pe.x >> LBITS, pe.y); // (col, prescaled val)
    }
}

// ---------------- fused per-layer SpMM + activation (byte-identical to R14) ----------------
__global__ void __launch_bounds__(256) k_layer(const int* __restrict__ row_ptr,
                                               const int2* __restrict__ packed,
                                               const float* __restrict__ state_in,
                                               const float* __restrict__ inp,
                                               float* __restrict__ plane_out,
                                               int t) {
    __shared__ int2 ebuf[16][17];               // [group][slot], +1 pad
    const int tid = threadIdx.x;
    const int g = tid >> 4, b = tid & 15;
    const int r = blockIdx.x * 16 + g;          // 6250*16 == N_NEURONS exactly
    const int s = row_ptr[r], e = row_ptr[r + 1];
    int acc = 0;
    int idx0 = s + b;
    int2 pe = (idx0 < e) ? packed[idx0] : make_int2(0, 0);
    for (int base = s; base < e; base += 16) {
        int nidx = base + 16 + b;               // prefetch next batch NOW
        int2 pe_next = (nidx < e) ? packed[nidx] : make_int2(0, 0);
        ebuf[g][b] = pe;                        // wave-lockstep, in-order DS pipe
        #pragma unroll
        for (int j = 0; j < 16; ++j) {
            int2 q = ebuf[g][j];                // 16-lane same-address broadcast read
            float prod = __int_as_float(q.y) * state_in[q.x * BATCH + b];
            acc += __float2int_rn(prod);        // UNBIASED quantization at 2^-28
        }
        pe = pe_next;
    }
    float y = (float)acc * FXI32;
    float a = activate(y);
    if (t < T_LAYERS - 1) {
        if (r < N_SENSORY) a += thresh_clamp_inp(inp[b * ST + r * T_LAYERS + (t + 1)]);
        a = fminf(a, 1.0f);                     // off-sensory no-op (|tanh|<1)
    }
    plane_out[r * BATCH + b] = a;
}

// ---------------- planes[t][n][b] -> out[b][n][t] ----------------
__global__ void k_out(const float* __restrict__ planes, float* __restrict__ out) {
    int i = blockIdx.x * blockDim.x + threadIdx.x;
    if (i >= NB) return;
    int n = i >> 4, b = i & 15;
    float4 o0, o1;
    o0.x = planes[0 * NB + i]; o0.y = planes[1 * NB + i];
    o0.z = planes[2 * NB + i]; o0.w = planes[3 * NB + i];
    o1.x = planes[4 * NB + i]; o1.y = planes[5 * NB + i];
    o1.z = planes[6 * NB + i]; o1.w = planes[7 * NB + i];
    float4* dst = (float4*)&out[b * NT + n * T_LAYERS];
    dst[0] = o0; dst[1] = o1;
}

// ---------------- fallback (atomic fixed-point path, 19.2 MB ws) ----------------
__global__ void k2_init(const float* __restrict__ inp, float* __restrict__ state,
                        long long* __restrict__ acc) {
    int stride = gridDim.x * blockDim.x;
    for (int i = blockIdx.x * blockDim.x + threadIdx.x; i < NB; i += stride) {
        int n = i >> 4, b = i & 15;
        float v = 0.0f;
        if (n < N_SENSORY) v = thresh_clamp_inp(inp[b * ST + n * T_LAYERS + 0]);
        state[i] = v;
        acc[i]   = 0LL;
    }
}
__global__ void __launch_bounds__(256) k2_spmm(const float* __restrict__ vals,
                                               const int* __restrict__ rows,
                                               const int* __restrict__ cols,
                                               const float* __restrict__ state,
                                               long long* acc) {
    int tid = blockIdx.x * blockDim.x + threadIdx.x;
    int b = tid & 15;
    int e = tid >> 4;
    int estride = (gridDim.x * blockDim.x) >> 4;
    for (; e < NNZ_CNT; e += estride) {
        float xv = state[cols[e] * BATCH + b];
        long long fx = llrintf(vals[e] * xv * FXSCALE);
        if (fx != 0LL)
            atomicAdd((unsigned long long*)&acc[rows[e] * BATCH + b], (unsigned long long)fx);
    }
}
__global__ void k2_act_inject(long long* acc, const float* __restrict__ inp,
                              float* __restrict__ state, float* __restrict__ out, int t) {
    int stride = gridDim.x * blockDim.x;
    for (int i = blockIdx.x * blockDim.x + threadIdx.x; i < NB; i += stride) {
        int n = i >> 4, b = i & 15;
        float y = (float)((double)acc[i] * FXINV);
        acc[i] = 0LL;
        float v = activate(y);
        if (n < N_SENSORY) v += thresh_clamp_inp(inp[b * ST + n * T_LAYERS + (t + 1)]);
        v = fminf(v, 1.0f);
        state[i] = v;
        out[b * NT + n * T_LAYERS + t] = v;
    }
}
__global__ void k2_act_final(const long long* __restrict__ acc, float* __restrict__ out) {
    int stride = gridDim.x * blockDim.x;
    for (int i = blockIdx.x * blockDim.x + threadIdx.x; i < NB; i += stride) {
        int n = i >> 4, b = i & 15;
        float y = (float)((double)acc[i] * FXINV);
        out[b * NT + n * T_LAYERS + (T_LAYERS - 1)] = activate(y);
    }
}

extern "C" void kernel_launch(void* const* d_in, const int* in_sizes, int n_in,
                              void* d_out, int out_size, void* d_ws, size_t ws_size,
                              hipStream_t stream) {
    const float* inputs = (const float*)d_in[0];
    const float* vals   = (const float*)d_in[1];
    const int*   rows   = (const int*)  d_in[2];
    const int*   cols   = (const int*)  d_in[3];
    float* out = (float*)d_out;

    const size_t sz_planes = (size_t)T_LAYERS * NB * 4;   // 51.2 MB (slab 28.9MB aliases planes[0..4])
    const size_t sz_packed = (size_t)NNZ_CNT * 8;         // 25.6 MB
    const size_t sz_rowptr = ((size_t)N_NEURONS + 2) * 4;
    const size_t sz_bt     = (size_t)(NBUCKET + 8) * 4;
    const size_t REQ = sz_planes + sz_packed + sz_rowptr + 2 * sz_bt;

    const int block = 256;

    if (ws_size >= REQ) {
        char* ws = (char*)d_ws;
        float* planes  = (float*)ws;
        int2*  packed  = (int2*)(ws + sz_planes);
        int*   row_ptr = (int*)(ws + sz_planes + sz_packed);
        int*   bbase   = (int*)(ws + sz_planes + sz_packed + sz_rowptr);
        int*   bcur    = (int*)(ws + sz_planes + sz_packed + sz_rowptr + sz_bt);
        float* state0  = planes + (size_t)(T_LAYERS - 1) * NB;  // planes[7], consumed at t=0
        int2*  slab    = (int2*)planes;   // 28.9 MB build scratch; dead before layers

        const int grid_nb = (NB + block - 1) / block;           // 6250

        k_init<<<grid_nb, block, 0, stream>>>(inputs, state0, bcur);
        k_passA<<<NBLK_A, 1024, 0, stream>>>(vals, rows, cols, bcur, slab);
        k_bscan2<<<1, 256, 0, stream>>>(bcur, bbase, row_ptr);
        k_passB<<<NBUCKET, 1024, 0, stream>>>(bcur, bbase, slab, packed, row_ptr);

        for (int t = 0; t < T_LAYERS; ++t) {
            const float* sin_ = (t == 0) ? state0 : planes + (size_t)(t - 1) * NB;
            k_layer<<<grid_nb, block, 0, stream>>>(row_ptr, packed, sin_, inputs,
                                                   planes + (size_t)t * NB, t);
        }
        k_out<<<grid_nb, block, 0, stream>>>(planes, out);
    } else {
        long long* acc   = (long long*)d_ws;
        float*     state = (float*)(acc + NB);
        const int grid_ew = 2048, grid_sp = 2048;
        k2_init<<<grid_ew, block, 0, stream>>>(inputs, state, acc);
        for (int t = 0; t < T_LAYERS; ++t) {
            k2_spmm<<<grid_sp, block, 0, stream>>>(vals, rows, cols, state, acc);
            if (t < T_LAYERS - 1)
                k2_act_inject<<<grid_ew, block, 0, stream>>>(acc, inputs, state, out, t);
            else
                k2_act_final<<<grid_ew, block, 0, stream>>>(acc, out);
        }
    }
}